// Round 1
// baseline (153.932 us; speedup 1.0000x reference)
//
#include <hip/hip_runtime.h>
#include <math.h>

// Problem constants (fixed by the reference)
// B=16384, D=1024, E=8, T=4, H=512
// Output: [T, B] f32 (65536 elements)

// ---------------- async global->LDS helpers ----------------
__device__ __forceinline__ void lds_load4(const float* g, float* l) {
  __builtin_amdgcn_global_load_lds((const __attribute__((address_space(1))) unsigned int*)g,
                                   (__attribute__((address_space(3))) unsigned int*)l, 4, 0, 0);
}
__device__ __forceinline__ void lds_load16(const float* g, float* l) {
  __builtin_amdgcn_global_load_lds((const __attribute__((address_space(1))) unsigned int*)g,
                                   (__attribute__((address_space(3))) unsigned int*)l, 16, 0, 0);
}

// ---------------- Precompute: Wcomb[1024][64] + cbias[32] in ws ----------------
// Wcomb[d][t*8+e]      = Wg[t][d][e]                      (gate columns)
// Wcomb[d][32+t*8+e]   = sum_h We[e][d][h] * Wt[t][h]     (folded score columns)
// cbias[t*8+e]         = sum_h be[e][h] * Wt[t][h]
// grid 2048 x 256; wave per pairid = e*1024 + d
__global__ __launch_bounds__(256) void mmoe_precompute(
    const float* __restrict__ We,   // [8][1024][512]
    const float* __restrict__ be,   // [8][512]
    const float* __restrict__ Wg,   // [4][1024][8]
    const float* __restrict__ Wt,   // [4][512]
    float* __restrict__ ws)
{
  float* Wcomb = ws;
  float* cbias = ws + 65536;

  const int tid  = threadIdx.x;
  const int lane = tid & 63;
  const int w    = tid >> 6;
  const int pairid = blockIdx.x * 4 + w;   // 0..8191
  const int e = pairid >> 10;
  const int d = pairid & 1023;

  // V[t,e,d] = sum_h We[e,d,h]*Wt[t,h]
  const float* werow = We + (size_t)pairid * 512;
  float a0 = 0.f, a1 = 0.f, a2 = 0.f, a3 = 0.f;
#pragma unroll
  for (int j = 0; j < 8; ++j) {
    int h = lane + j * 64;
    float wv = werow[h];
    a0 = fmaf(wv, Wt[h],        a0);
    a1 = fmaf(wv, Wt[512 + h],  a1);
    a2 = fmaf(wv, Wt[1024 + h], a2);
    a3 = fmaf(wv, Wt[1536 + h], a3);
  }
#pragma unroll
  for (int m = 1; m < 64; m <<= 1) {
    a0 += __shfl_xor(a0, m, 64);
    a1 += __shfl_xor(a1, m, 64);
    a2 += __shfl_xor(a2, m, 64);
    a3 += __shfl_xor(a3, m, 64);
  }
  if (lane == 0) {
    Wcomb[d * 64 + 32 + 0 * 8 + e] = a0;
    Wcomb[d * 64 + 32 + 1 * 8 + e] = a1;
    Wcomb[d * 64 + 32 + 2 * 8 + e] = a2;
    Wcomb[d * 64 + 32 + 3 * 8 + e] = a3;
  }

  // gate columns (once per d: only the e==0 waves)
  if (e == 0 && lane < 32) {
    int t = lane >> 3, ee = lane & 7;
    Wcomb[d * 64 + t * 8 + ee] = Wg[t * 8192 + d * 8 + ee];
  }

  // cbias (once per e: only the d==0 waves)
  if (d == 0) {
    float b0 = 0.f, b1 = 0.f, b2 = 0.f, b3 = 0.f;
#pragma unroll
    for (int j = 0; j < 8; ++j) {
      int h = lane + j * 64;
      float bv = be[e * 512 + h];
      b0 = fmaf(bv, Wt[h],        b0);
      b1 = fmaf(bv, Wt[512 + h],  b1);
      b2 = fmaf(bv, Wt[1024 + h], b2);
      b3 = fmaf(bv, Wt[1536 + h], b3);
    }
#pragma unroll
    for (int m = 1; m < 64; m <<= 1) {
      b0 += __shfl_xor(b0, m, 64);
      b1 += __shfl_xor(b1, m, 64);
      b2 += __shfl_xor(b2, m, 64);
      b3 += __shfl_xor(b3, m, 64);
    }
    if (lane == 0) {
      cbias[0 * 8 + e] = b0;
      cbias[1 * 8 + e] = b1;
      cbias[2 * 8 + e] = b2;
      cbias[3 * 8 + e] = b3;
    }
  }
}

// ---------------- Main: Y = x @ Wcomb, fused softmax-mix epilogue ----------------
// grid 512 x 256. Block tile: 32 b-rows x 64 cols, K=1024 in 16 chunks of 64.
// 4 waves k-split each chunk (wave w takes its 16 k's); per-thread 4b x 8n tile.
// LDS floats: buf0 X [0,2048) W [2048,6144); buf1 X [6144,8192) W [8192,12288).
// Epilogue reduction reuses [0,8192) as Yred[4][32][64].
__global__ __launch_bounds__(256, 2) void mmoe_main(
    const float* __restrict__ x,     // [16384][1024]
    const float* __restrict__ bgp,   // [4][8]
    const float* __restrict__ btp,   // [4]
    const float* __restrict__ ws,    // Wcomb + cbias
    float* __restrict__ out)         // [4][16384]
{
  __shared__ float lds[12288];
  const float* Wcomb = ws;
  const float* cbias = ws + 65536;

  const int tid  = threadIdx.x;
  const int lane = tid & 63;
  const int w    = tid >> 6;   // wave 0..3
  const int bgi  = lane >> 3;  // b-group 0..7
  const int ngi  = lane & 7;   // n-group 0..7
  const int b0   = blockIdx.x * 32;

  float acc[4][8];
#pragma unroll
  for (int i = 0; i < 4; ++i)
#pragma unroll
    for (int j = 0; j < 8; ++j) acc[i][j] = 0.f;

  const int xrow = b0 + (lane & 31);
  const int ksub = lane >> 5;
  const float* xlanebase = x + (size_t)xrow * 1024 + ksub;

  // stage chunk c into buffer (bx = X base, bw = W base); 12 loads per wave
  auto stage = [&](int bx, int bw, int c) {
    const float* xsrc = xlanebase + c * 64;
#pragma unroll
    for (int i = 0; i < 8; ++i) {
      int inst = w * 8 + i;                         // 0..31
      lds_load4(xsrc + inst * 2, lds + bx + inst * 64);
    }
    const float* wsrc = Wcomb + c * 4096 + lane * 4;
#pragma unroll
    for (int i = 0; i < 4; ++i) {
      int inst = w * 4 + i;                         // 0..15
      lds_load16(wsrc + inst * 256, lds + bw + inst * 256);
    }
  };

  auto compute = [&](int bx, int bw) {
    const int kbase = w * 16;
#pragma unroll
    for (int kk = 0; kk < 16; ++kk) {
      int k = kbase + kk;
      const float4 xf = *(const float4*)(lds + bx + k * 32 + bgi * 4);
      const float4 wa = *(const float4*)(lds + bw + k * 64 + ngi * 8);
      const float4 wb = *(const float4*)(lds + bw + k * 64 + ngi * 8 + 4);
      float xv[4] = {xf.x, xf.y, xf.z, xf.w};
      float wv[8] = {wa.x, wa.y, wa.z, wa.w, wb.x, wb.y, wb.z, wb.w};
#pragma unroll
      for (int i = 0; i < 4; ++i)
#pragma unroll
        for (int j = 0; j < 8; ++j)
          acc[i][j] = fmaf(xv[i], wv[j], acc[i][j]);
    }
  };

  stage(0, 2048, 0);
#pragma unroll 2
  for (int c = 0; c < 16; ++c) {
    const int pb = c & 1;
    const int bx = pb ? 6144 : 0;
    const int bw = pb ? 8192 : 2048;
    const int nx = pb ? 0 : 6144;
    const int nw = pb ? 2048 : 8192;
    if (c < 15) {
      stage(nx, nw, c + 1);
      asm volatile("s_waitcnt vmcnt(12)" ::: "memory");  // wait current buf only
    } else {
      asm volatile("s_waitcnt vmcnt(0)" ::: "memory");
    }
    __builtin_amdgcn_s_barrier();
    compute(bx, bw);
    asm volatile("s_waitcnt lgkmcnt(0)" ::: "memory");
    __builtin_amdgcn_s_barrier();
  }

  // ---- cross-wave reduction + epilogue ----
#pragma unroll
  for (int i = 0; i < 4; ++i) {
    int row = bgi * 4 + i;
    *(float4*)(lds + w * 2048 + row * 64 + ngi * 8) =
        make_float4(acc[i][0], acc[i][1], acc[i][2], acc[i][3]);
    *(float4*)(lds + w * 2048 + row * 64 + ngi * 8 + 4) =
        make_float4(acc[i][4], acc[i][5], acc[i][6], acc[i][7]);
  }
  __syncthreads();

  if (tid < 128) {
    const int b = tid & 31;
    const int t = tid >> 5;
    float gv[8], sv[8];
#pragma unroll
    for (int e = 0; e < 8; ++e) {
      float gg = 0.f, ss = 0.f;
#pragma unroll
      for (int wv2 = 0; wv2 < 4; ++wv2) {
        gg += lds[wv2 * 2048 + b * 64 + t * 8 + e];
        ss += lds[wv2 * 2048 + b * 64 + 32 + t * 8 + e];
      }
      gv[e] = gg + bgp[t * 8 + e];
      sv[e] = ss + cbias[t * 8 + e];
    }
    float m = gv[0];
#pragma unroll
    for (int e = 1; e < 8; ++e) m = fmaxf(m, gv[e]);
    float Z = 0.f, num = 0.f;
#pragma unroll
    for (int e = 0; e < 8; ++e) {
      float p = __expf(gv[e] - m);
      Z += p;
      num = fmaf(p, sv[e], num);
    }
    out[t * 16384 + b0 + b] = num / Z + btp[t];
  }
}

extern "C" void kernel_launch(void* const* d_in, const int* in_sizes, int n_in,
                              void* d_out, int out_size, void* d_ws, size_t ws_size,
                              hipStream_t stream) {
  const float* x  = (const float*)d_in[0];
  const float* We = (const float*)d_in[1];
  const float* be = (const float*)d_in[2];
  const float* Wg = (const float*)d_in[3];
  const float* bg = (const float*)d_in[4];
  const float* Wt = (const float*)d_in[5];
  const float* bt = (const float*)d_in[6];
  float* out = (float*)d_out;
  float* ws  = (float*)d_ws;   // needs 65568 floats (~257 KB)

  hipLaunchKernelGGL(mmoe_precompute, dim3(2048), dim3(256), 0, stream, We, be, Wg, Wt, ws);
  hipLaunchKernelGGL(mmoe_main, dim3(512), dim3(256), 0, stream, x, bg, bt, ws, out);
}

// Round 2
// 135.177 us; speedup vs baseline: 1.1387x; 1.1387x over previous
//
#include <hip/hip_runtime.h>
#include <math.h>

// B=16384, D=1024, E=8, T=4, H=512. Output [T,B] f32.
// ws layout: [0,65536) floats  Wcomb f32 [d][64] (cols 0-31 gates t*8+e, 32-63 scores)
//            [65536,65568)     cbias[t*8+e]
//            bytes 262272+     Wfrag: 32 ksteps x {hi,lo}x{nf0..3} x 64 lanes x 8 bf16 (256 KB)

typedef float  f32x4  __attribute__((ext_vector_type(4)));
typedef short  bf16x8 __attribute__((ext_vector_type(8)));

#define WFRAG_OFF_BYTES 262272

__device__ __forceinline__ void cvt_pair(float f0, float f1, unsigned int& hi, unsigned int& lo) {
  unsigned int u0 = __float_as_uint(f0), u1 = __float_as_uint(f1);
  unsigned int r0 = u0 + 0x7FFFu + ((u0 >> 16) & 1u);
  unsigned int r1 = u1 + 0x7FFFu + ((u1 >> 16) & 1u);
  float h0 = __uint_as_float(r0 & 0xFFFF0000u);
  float h1 = __uint_as_float(r1 & 0xFFFF0000u);
  hi = (r0 >> 16) | (r1 & 0xFFFF0000u);
  float l0 = f0 - h0, l1 = f1 - h1;
  unsigned int s0 = __float_as_uint(l0), s1 = __float_as_uint(l1);
  unsigned int q0 = s0 + 0x7FFFu + ((s0 >> 16) & 1u);
  unsigned int q1 = s1 + 0x7FFFu + ((s1 >> 16) & 1u);
  lo = (q0 >> 16) | (q1 & 0xFFFF0000u);
}

// ---------------- Precompute Wcomb f32 + cbias (unchanged from R1, verified) ----------------
__global__ __launch_bounds__(256) void mmoe_precompute(
    const float* __restrict__ We, const float* __restrict__ be,
    const float* __restrict__ Wg, const float* __restrict__ Wt,
    float* __restrict__ ws)
{
  float* Wcomb = ws;
  float* cbias = ws + 65536;
  const int tid = threadIdx.x, lane = tid & 63, w = tid >> 6;
  const int pairid = blockIdx.x * 4 + w;
  const int e = pairid >> 10, d = pairid & 1023;

  const float* werow = We + (size_t)pairid * 512;
  float a0 = 0.f, a1 = 0.f, a2 = 0.f, a3 = 0.f;
#pragma unroll
  for (int j = 0; j < 8; ++j) {
    int h = lane + j * 64;
    float wv = werow[h];
    a0 = fmaf(wv, Wt[h],        a0);
    a1 = fmaf(wv, Wt[512 + h],  a1);
    a2 = fmaf(wv, Wt[1024 + h], a2);
    a3 = fmaf(wv, Wt[1536 + h], a3);
  }
#pragma unroll
  for (int m = 1; m < 64; m <<= 1) {
    a0 += __shfl_xor(a0, m, 64); a1 += __shfl_xor(a1, m, 64);
    a2 += __shfl_xor(a2, m, 64); a3 += __shfl_xor(a3, m, 64);
  }
  if (lane == 0) {
    Wcomb[d * 64 + 32 + 0 * 8 + e] = a0;
    Wcomb[d * 64 + 32 + 1 * 8 + e] = a1;
    Wcomb[d * 64 + 32 + 2 * 8 + e] = a2;
    Wcomb[d * 64 + 32 + 3 * 8 + e] = a3;
  }
  if (e == 0 && lane < 32) {
    int t = lane >> 3, ee = lane & 7;
    Wcomb[d * 64 + t * 8 + ee] = Wg[t * 8192 + d * 8 + ee];
  }
  if (d == 0) {
    float b0 = 0.f, b1 = 0.f, b2 = 0.f, b3 = 0.f;
#pragma unroll
    for (int j = 0; j < 8; ++j) {
      int h = lane + j * 64;
      float bv = be[e * 512 + h];
      b0 = fmaf(bv, Wt[h],        b0);
      b1 = fmaf(bv, Wt[512 + h],  b1);
      b2 = fmaf(bv, Wt[1024 + h], b2);
      b3 = fmaf(bv, Wt[1536 + h], b3);
    }
#pragma unroll
    for (int m = 1; m < 64; m <<= 1) {
      b0 += __shfl_xor(b0, m, 64); b1 += __shfl_xor(b1, m, 64);
      b2 += __shfl_xor(b2, m, 64); b3 += __shfl_xor(b3, m, 64);
    }
    if (lane == 0) {
      cbias[0 * 8 + e] = b0; cbias[1 * 8 + e] = b1;
      cbias[2 * 8 + e] = b2; cbias[3 * 8 + e] = b3;
    }
  }
}

// ---------------- Swizzle Wcomb -> bf16 hi/lo MFMA B-fragments ----------------
// Slot idx = ks*512 + vn*64 + lane; vn = v*4+nf (v:0=hi,1=lo). Lane l holds
// B[k = ks*32 + (l>>4)*8 + j][n = nf*16 + (l&15)], j=0..7, packed 2 bf16/u32.
__global__ __launch_bounds__(256) void mmoe_swizzle(const float* __restrict__ Wc,
                                                    uint4* __restrict__ wf)
{
  const int idx = blockIdx.x * 256 + threadIdx.x;  // 0..16383
  const int ks = idx >> 9;
  const int rem = idx & 511;
  const int vn = rem >> 6, l = rem & 63;
  const int v = vn >> 2, nf = vn & 3;
  const int n = nf * 16 + (l & 15);
  const int kbase = ks * 32 + (l >> 4) * 8;
  unsigned int pk[4];
#pragma unroll
  for (int p = 0; p < 4; ++p) {
    float f0 = Wc[(size_t)(kbase + 2 * p) * 64 + n];
    float f1 = Wc[(size_t)(kbase + 2 * p + 1) * 64 + n];
    unsigned int hi, lo;
    cvt_pair(f0, f1, hi, lo);
    pk[p] = v ? lo : hi;
  }
  uint4 val; val.x = pk[0]; val.y = pk[1]; val.z = pk[2]; val.w = pk[3];
  wf[idx] = val;
}

// ---------------- Main: 1024 single-wave blocks, 16 rows x 64 cols each ----------------
__global__ __launch_bounds__(64, 1) void mmoe_main(
    const float* __restrict__ x,
    const float* __restrict__ bgp,   // [4][8]
    const float* __restrict__ btp,   // [4]
    const float* __restrict__ ws,
    float* __restrict__ out)
{
  __shared__ float cmat[1024];   // [16 rows][64 cols]
  const int l  = threadIdx.x;
  const int b0g = blockIdx.x * 16;
  const float* cbias = ws + 65536;
  const bf16x8* __restrict__ bptr =
      (const bf16x8*)((const unsigned char*)ws + WFRAG_OFF_BYTES);

  // lane's A-fragment source: row = l&15, k-octet = (l>>4)*8
  const float4* __restrict__ xptr =
      (const float4*)(x + (size_t)(b0g + (l & 15)) * 1024) + (l >> 4) * 2;

  float4 xbuf[4][2];
  bf16x8 breg[2][8];
  f32x4  acc[4];
#pragma unroll
  for (int nf = 0; nf < 4; ++nf) acc[nf] = (f32x4){0.f, 0.f, 0.f, 0.f};

  // prologue: x steps 0..3, B steps 0..1
#pragma unroll
  for (int p = 0; p < 4; ++p) { xbuf[p][0] = xptr[p * 8]; xbuf[p][1] = xptr[p * 8 + 1]; }
#pragma unroll
  for (int vn = 0; vn < 8; ++vn) breg[0][vn] = bptr[vn * 64 + l];
#pragma unroll
  for (int vn = 0; vn < 8; ++vn) breg[1][vn] = bptr[512 + vn * 64 + l];

  union UC { unsigned int u[4]; bf16x8 v; };

#define STEP(S)                                                                      \
  {                                                                                  \
    float4 xa = xbuf[(S) & 3][0], xb = xbuf[(S) & 3][1];                             \
    if ((S) + 4 < 32) {                                                              \
      xbuf[(S) & 3][0] = xptr[((S) + 4) * 8];                                        \
      xbuf[(S) & 3][1] = xptr[((S) + 4) * 8 + 1];                                    \
    }                                                                                \
    UC Ah, Al;                                                                       \
    cvt_pair(xa.x, xa.y, Ah.u[0], Al.u[0]);                                          \
    cvt_pair(xa.z, xa.w, Ah.u[1], Al.u[1]);                                          \
    cvt_pair(xb.x, xb.y, Ah.u[2], Al.u[2]);                                          \
    cvt_pair(xb.z, xb.w, Ah.u[3], Al.u[3]);                                          \
    acc[0] = __builtin_amdgcn_mfma_f32_16x16x32_bf16(Ah.v, breg[(S) & 1][0], acc[0], 0, 0, 0); \
    acc[1] = __builtin_amdgcn_mfma_f32_16x16x32_bf16(Ah.v, breg[(S) & 1][1], acc[1], 0, 0, 0); \
    acc[2] = __builtin_amdgcn_mfma_f32_16x16x32_bf16(Ah.v, breg[(S) & 1][2], acc[2], 0, 0, 0); \
    acc[3] = __builtin_amdgcn_mfma_f32_16x16x32_bf16(Ah.v, breg[(S) & 1][3], acc[3], 0, 0, 0); \
    acc[0] = __builtin_amdgcn_mfma_f32_16x16x32_bf16(Ah.v, breg[(S) & 1][4], acc[0], 0, 0, 0); \
    acc[1] = __builtin_amdgcn_mfma_f32_16x16x32_bf16(Ah.v, breg[(S) & 1][5], acc[1], 0, 0, 0); \
    acc[2] = __builtin_amdgcn_mfma_f32_16x16x32_bf16(Ah.v, breg[(S) & 1][6], acc[2], 0, 0, 0); \
    acc[3] = __builtin_amdgcn_mfma_f32_16x16x32_bf16(Ah.v, breg[(S) & 1][7], acc[3], 0, 0, 0); \
    acc[0] = __builtin_amdgcn_mfma_f32_16x16x32_bf16(Al.v, breg[(S) & 1][0], acc[0], 0, 0, 0); \
    acc[1] = __builtin_amdgcn_mfma_f32_16x16x32_bf16(Al.v, breg[(S) & 1][1], acc[1], 0, 0, 0); \
    acc[2] = __builtin_amdgcn_mfma_f32_16x16x32_bf16(Al.v, breg[(S) & 1][2], acc[2], 0, 0, 0); \
    acc[3] = __builtin_amdgcn_mfma_f32_16x16x32_bf16(Al.v, breg[(S) & 1][3], acc[3], 0, 0, 0); \
    if ((S) + 2 < 32) {                                                              \
      _Pragma("unroll")                                                              \
      for (int vn = 0; vn < 8; ++vn)                                                 \
        breg[(S) & 1][vn] = bptr[((S) + 2) * 512 + vn * 64 + l];                     \
    }                                                                                \
  }

  STEP(0)  STEP(1)  STEP(2)  STEP(3)  STEP(4)  STEP(5)  STEP(6)  STEP(7)
  STEP(8)  STEP(9)  STEP(10) STEP(11) STEP(12) STEP(13) STEP(14) STEP(15)
  STEP(16) STEP(17) STEP(18) STEP(19) STEP(20) STEP(21) STEP(22) STEP(23)
  STEP(24) STEP(25) STEP(26) STEP(27) STEP(28) STEP(29) STEP(30) STEP(31)
#undef STEP

  // ---- epilogue: C frag (col=lane&15, row=(lane>>4)*4+r) -> LDS -> softmax-mix ----
#pragma unroll
  for (int nf = 0; nf < 4; ++nf)
#pragma unroll
    for (int r = 0; r < 4; ++r)
      cmat[((l >> 4) * 4 + r) * 64 + nf * 16 + (l & 15)] = acc[nf][r];
  __syncthreads();

  const int row = l >> 2, t = l & 3;
  const float4 ga = *(const float4*)&cmat[row * 64 + t * 8];
  const float4 gb = *(const float4*)&cmat[row * 64 + t * 8 + 4];
  const float4 sa = *(const float4*)&cmat[row * 64 + 32 + t * 8];
  const float4 sb = *(const float4*)&cmat[row * 64 + 32 + t * 8 + 4];
  float g[8] = {ga.x, ga.y, ga.z, ga.w, gb.x, gb.y, gb.z, gb.w};
  float s[8] = {sa.x, sa.y, sa.z, sa.w, sb.x, sb.y, sb.z, sb.w};
#pragma unroll
  for (int e = 0; e < 8; ++e) {
    g[e] += bgp[t * 8 + e];
    s[e] += cbias[t * 8 + e];
  }
  float m = g[0];
#pragma unroll
  for (int e = 1; e < 8; ++e) m = fmaxf(m, g[e]);
  float Z = 0.f, num = 0.f;
#pragma unroll
  for (int e = 0; e < 8; ++e) {
    float p = __expf(g[e] - m);
    Z += p;
    num = fmaf(p, s[e], num);
  }
  out[t * 16384 + b0g + row] = num / Z + btp[t];
}

extern "C" void kernel_launch(void* const* d_in, const int* in_sizes, int n_in,
                              void* d_out, int out_size, void* d_ws, size_t ws_size,
                              hipStream_t stream) {
  const float* x  = (const float*)d_in[0];
  const float* We = (const float*)d_in[1];
  const float* be = (const float*)d_in[2];
  const float* Wg = (const float*)d_in[3];
  const float* bg = (const float*)d_in[4];
  const float* Wt = (const float*)d_in[5];
  const float* bt = (const float*)d_in[6];
  float* out = (float*)d_out;
  float* ws  = (float*)d_ws;   // needs 524416 bytes

  uint4* wf = (uint4*)((unsigned char*)d_ws + WFRAG_OFF_BYTES);

  hipLaunchKernelGGL(mmoe_precompute, dim3(2048), dim3(256), 0, stream, We, be, Wg, Wt, ws);
  hipLaunchKernelGGL(mmoe_swizzle,    dim3(64),   dim3(256), 0, stream, ws, wf);
  hipLaunchKernelGGL(mmoe_main,       dim3(1024), dim3(64),  0, stream, x, bg, bt, ws, out);
}